// Round 5
// baseline (256.751 us; speedup 1.0000x reference)
//
#include <hip/hip_runtime.h>
#include <math.h>

// Problem constants
#define OUT_TAIL (16*8*256*256)   // logdet lives after the output tensor
#define HSTR   68                 // bf16 elems per H row (64 + 4 pad) -> odd dword-pair stride, b64 conflict-free
#define HROWB  136                // bytes per H row
#define SSTRIDE 2176              // 16 rows * HROWB = strip stride in bytes
#define INSTR  408                // in_s per-channel stride (shorts)

typedef __bf16 bf8_t __attribute__((ext_vector_type(8)));
typedef float  f4_t  __attribute__((ext_vector_type(4)));

__device__ __forceinline__ unsigned rne16u_(float x) {
    unsigned u = __float_as_uint(x);
    return (u + 0x7fffu + ((u >> 16) & 1u)) >> 16;
}
#if __has_builtin(__builtin_amdgcn_cvt_pk_bf16_f32)
__device__ __forceinline__ unsigned pack2f(float a, float b) {
    typedef __bf16 bf2_t __attribute__((ext_vector_type(2)));
    bf2_t r = __builtin_amdgcn_cvt_pk_bf16_f32(a, b);
    return __builtin_bit_cast(unsigned, r);
}
#else
__device__ __forceinline__ unsigned pack2f(float a, float b) {
    unsigned r;
    asm("v_cvt_pk_bf16_f32 %0, %1, %2" : "=v"(r) : "v"(a), "v"(b));
    return r;
}
#endif
__device__ __forceinline__ bf8_t as_bf8(uint4 u) { return __builtin_bit_cast(bf8_t, u); }

// ---------------- prep: split weights into hi/lo bf16 MFMA A-fragments ----------------
// frag ids: conv0: 0..7 (Mt*2+ks) ; layers1-4: 8+l*8+Mt*2+ks ; convz: 40+tap*2+ks
// record: [frag][lane][hi u32 x4 | lo u32 x4]
__global__ void prep_kernel(const float* __restrict__ w0, const float* __restrict__ w1,
                            const float* __restrict__ w2, const float* __restrict__ w3,
                            const float* __restrict__ w4, const float* __restrict__ wz,
                            unsigned int* __restrict__ ws) {
    int f = blockIdx.x;          // 0..57
    int lane = threadIdx.x;      // 0..63
    int m = lane & 15, qd = lane >> 4;
    float vals[8];
    if (f < 8) {                 // conv0: K = ch*9+tap, 54 real
        int Mt = f >> 1, ks = f & 1;
        int c = Mt * 16 + m;
        for (int j = 0; j < 8; ++j) {
            int k = ks * 32 + qd * 8 + j;
            vals[j] = (k < 54) ? w0[c * 54 + k] : 0.0f;
        }
    } else if (f < 40) {         // 1x1 layers
        int r = f - 8, l = r >> 3, fr = r & 7;
        int Mt = fr >> 1, ks = fr & 1;
        const float* wp = (l == 0) ? w1 : (l == 1) ? w2 : (l == 2) ? w3 : w4;
        int c = Mt * 16 + m;
        for (int j = 0; j < 8; ++j) vals[j] = wp[c * 64 + ks * 32 + qd * 8 + j];
    } else {                     // convz: per-tap
        int r = f - 40, tap = r >> 1, ks = r & 1;
        for (int j = 0; j < 8; ++j) {
            int k = ks * 32 + qd * 8 + j;
            vals[j] = wz[(m * 64 + k) * 9 + tap];
        }
    }
    unsigned int hi[4], lo[4];
    for (int i = 0; i < 4; ++i) {
        float a = vals[2 * i], c = vals[2 * i + 1];
        unsigned ha = rne16u_(a), hc = rne16u_(c);
        float ra = a - __uint_as_float(ha << 16);
        float rc = c - __uint_as_float(hc << 16);
        hi[i] = ha | (hc << 16);
        lo[i] = rne16u_(ra) | (rne16u_(rc) << 16);
    }
    unsigned int* p = ws + (size_t)(f * 64 + lane) * 8;
    for (int i = 0; i < 4; ++i) { p[i] = hi[i]; p[4 + i] = lo[i]; }
}

__global__ void init_logdet_kernel(const float* __restrict__ logdet, float* __restrict__ outp) {
    int i = threadIdx.x;
    if (i < 16) outp[OUT_TAIL + i] = logdet[i];
}

// ---------------- fused main kernel ----------------
// One block = one (batch, 16x16 tile). 512 threads = 8 waves (TLP: 2 blocks/CU = 16 waves).
// Waves 0-4 own 3 strips (48 px), waves 5-7 own 2 strips (32 px): 336 pixels total.
// LDS: Hs[336][68] bf16 (45696 B) + in_s[2464] bf16 (4928 B) + red -> ~50.7 KB
__global__ __launch_bounds__(512, 4)
void fused_kernel(const float* __restrict__ input, const float* __restrict__ ft,
                  const float* __restrict__ b0, const float* __restrict__ b1,
                  const float* __restrict__ b2, const float* __restrict__ b3,
                  const float* __restrict__ b4, const float* __restrict__ bz,
                  const float* __restrict__ logs, const unsigned int* __restrict__ wsp,
                  float* __restrict__ outp)
{
    __shared__ __align__(16) unsigned short Hs[336 * HSTR];
    __shared__ __align__(16) unsigned short in_s[2464];
    __shared__ float red[8];

    const int tid = threadIdx.x;
    const int bx = blockIdx.x, by = blockIdx.y, b = blockIdx.z;
    const int lane = tid & 63;
    const int ws_ = __builtin_amdgcn_readfirstlane(tid >> 6);   // wave id 0..7, scalar
    const int m = lane & 15, q = lane >> 4;
    const uint4* W4 = (const uint4*)wsp;
    const bool border = (bx == 0) | (bx == 15) | (by == 0) | (by == 15);

    // ---------------- stage input tile (bf16) + z1 fp32 passthrough ----------------
    {
        const int x0 = bx * 16 - 2, y0 = by * 16 - 2;
        for (int idx = tid; idx < 2400; idx += 512) {
            int c = idx / 400, r = idx - c * 400;
            int yy = r / 20, xx = r - yy * 20;
            int gy = y0 + yy, gx = x0 + xx;
            float v = 0.0f;
            if ((unsigned)gy < 256u && (unsigned)gx < 256u)
                v = (c < 4) ? input[((size_t)(b * 8 + c) * 256 + gy) * 256 + gx]
                            : ft[((size_t)(b * 2 + (c - 4)) * 256 + gy) * 256 + gx];
            in_s[c * INSTR + yy * 20 + xx] = (unsigned short)(pack2f(v, 0.0f) & 0xffffu);
        }
        // z1 exact fp32 passthrough: 2 floats per thread (1024 total)
        int idx = tid * 2;
        int c = idx >> 8, q2 = idx & 255;
        int oy = q2 >> 4, ox = q2 & 15;
        size_t o = ((size_t)(b * 8 + c) * 256 + by * 16 + oy) * 256 + bx * 16 + ox;
        *(float2*)&outp[o] = *(const float2*)&input[o];
    }
    __syncthreads();

    const int nstrip = (ws_ < 5) ? 3 : 2;
    const int pbase  = (ws_ < 5) ? (48 * ws_) : (240 + 32 * (ws_ - 5));
    const int pix0   = pbase + m;
    const int A0 = pix0 * HROWB + q * 16;   // H B-read base (bytes)
    const int W0 = pix0 * HROWB + q * 8;    // H write base (bytes); + s*SSTRIDE + Mt*32

    // ---------------- conv0 3x3 (6->64) via MFMA (hi-only), im2col gather from in_s ----------------
    {
        int koffB[16];                      // byte offsets into in_s, per-lane (q-dependent)
        #pragma unroll
        for (int ks = 0; ks < 2; ++ks)
            #pragma unroll
            for (int j = 0; j < 8; ++j) {
                int k = ks * 32 + q * 8 + j;
                int ch = k / 9, tap = k - ch * 9;
                int ky = tap / 3, kx = tap - ky * 3;
                koffB[ks * 8 + j] = (k < 54) ? (ch * INSTR + ky * 20 + kx) * 2 : 0;
            }
        uint4 Ah[8];
        #pragma unroll
        for (int f = 0; f < 8; ++f)
            Ah[f] = W4[((size_t)(f * 64) + lane) * 2];
        f4_t bv4[4];
        #pragma unroll
        for (int Mt = 0; Mt < 4; ++Mt)
            #pragma unroll
            for (int r = 0; r < 4; ++r) bv4[Mt][r] = b0[Mt * 16 + q * 4 + r];

        int cpy = (pix0 * 1821) >> 15;      // pix0 / 18 (exact for 0..335)
        int cpx = pix0 - cpy * 18;
        #pragma unroll
        for (int s = 0; s < 3; ++s) {
            if (s < nstrip) {
                int ib = (cpy * 20 + cpx) * 2;
                unsigned e[16];
                #pragma unroll
                for (int i = 0; i < 16; ++i)
                    e[i] = *(const unsigned short*)((const char*)in_s + ib + koffB[i]);
                uint4 B0 = make_uint4(e[0] | (e[1] << 16), e[2] | (e[3] << 16),
                                      e[4] | (e[5] << 16), e[6] | (e[7] << 16));
                uint4 B1 = make_uint4(e[8] | (e[9] << 16), e[10] | (e[11] << 16),
                                      e[12] | (e[13] << 16), e[14] | (e[15] << 16));
                #pragma unroll
                for (int Mt = 0; Mt < 4; ++Mt) {
                    f4_t a = __builtin_amdgcn_mfma_f32_16x16x32_bf16(as_bf8(Ah[Mt*2+0]), as_bf8(B0), bv4[Mt], 0, 0, 0);
                    a = __builtin_amdgcn_mfma_f32_16x16x32_bf16(as_bf8(Ah[Mt*2+1]), as_bf8(B1), a, 0, 0, 0);
                    uint2 pr;
                    pr.x = pack2f(fmaxf(a[0], 0.f), fmaxf(a[1], 0.f));
                    pr.y = pack2f(fmaxf(a[2], 0.f), fmaxf(a[3], 0.f));
                    *(uint2*)((char*)Hs + W0 + s * SSTRIDE + Mt * 32) = pr;
                }
            }
            cpx += 16;
            if (cpx >= 18) { cpx -= 18; cpy += 1; }
        }
    }

    // ---------------- 4x (1x1 conv 64->64 + ReLU) via MFMA (hi-only), in-place H, no barriers ----------------
    #pragma unroll 1
    for (int l = 0; l < 4; ++l) {
        const float* bl = (l == 0) ? b1 : (l == 1) ? b2 : (l == 2) ? b3 : b4;
        uint4 Ah[8];
        #pragma unroll
        for (int f = 0; f < 8; ++f)
            Ah[f] = W4[((size_t)((8 + l * 8 + f) * 64) + lane) * 2];
        f4_t bv4[4];
        #pragma unroll
        for (int Mt = 0; Mt < 4; ++Mt)
            #pragma unroll
            for (int r = 0; r < 4; ++r) bv4[Mt][r] = bl[Mt * 16 + q * 4 + r];

        #pragma unroll
        for (int s = 0; s < 3; ++s) {
            if (s < nstrip) {
                const char* rp = (const char*)Hs + A0 + s * SSTRIDE;
                uint2 a0 = *(const uint2*)(rp);
                uint2 a1 = *(const uint2*)(rp + 8);
                uint2 a2 = *(const uint2*)(rp + 64);
                uint2 a3 = *(const uint2*)(rp + 72);
                uint4 B0 = make_uint4(a0.x, a0.y, a1.x, a1.y);
                uint4 B1 = make_uint4(a2.x, a2.y, a3.x, a3.y);
                #pragma unroll
                for (int Mt = 0; Mt < 4; ++Mt) {
                    f4_t a = __builtin_amdgcn_mfma_f32_16x16x32_bf16(as_bf8(Ah[Mt*2+0]), as_bf8(B0), bv4[Mt], 0, 0, 0);
                    a = __builtin_amdgcn_mfma_f32_16x16x32_bf16(as_bf8(Ah[Mt*2+1]), as_bf8(B1), a, 0, 0, 0);
                    uint2 pr;
                    pr.x = pack2f(fmaxf(a[0], 0.f), fmaxf(a[1], 0.f));
                    pr.y = pack2f(fmaxf(a[2], 0.f), fmaxf(a[3], 0.f));
                    *(uint2*)((char*)Hs + W0 + s * SSTRIDE + Mt * 32) = pr;
                }
            }
        }
    }

    // ---------------- border blocks: zero H rows outside the image (convz zero-pad) ----------------
    if (border) {
        #pragma unroll
        for (int s = 0; s < 3; ++s) {
            if (s < nstrip) {
                int pixs = pix0 + 16 * s;
                int pys = (pixs * 1821) >> 15;
                int pxs = pixs - pys * 18;
                int gy = by * 16 - 1 + pys, gx = bx * 16 - 1 + pxs;
                if (!(((unsigned)gy < 256u) && ((unsigned)gx < 256u))) {
                    char* zp = (char*)Hs + A0 + s * SSTRIDE;   // q-chunks cover all 64 ch
                    *(uint2*)(zp)      = make_uint2(0, 0);
                    *(uint2*)(zp + 8)  = make_uint2(0, 0);
                    *(uint2*)(zp + 64) = make_uint2(0, 0);
                    *(uint2*)(zp + 72) = make_uint2(0, 0);
                }
            }
        }
    }
    __syncthreads();

    // ---------------- convz 3x3 (64->16) via MFMA (hi+lo) + RQ spline (shuffle-free epilogue) ----------------
    {
        // prefetch spline inputs x (z2 channels) and per-channel constants; wave owns 2 output rows
        float xv[2];
        #pragma unroll
        for (int rr = 0; rr < 2; ++rr) {
            int gy = by * 16 + ws_ * 2 + rr;
            xv[rr] = input[((size_t)(b * 8 + 4 + q) * 256 + gy) * 256 + bx * 16 + m];
        }
        float bzv[4], scl[4];
        #pragma unroll
        for (int r = 0; r < 4; ++r) {
            int c = q * 4 + r;
            bzv[r] = bz[c];
            scl[r] = __expf(3.0f * logs[c]);
        }
        f4_t acc[2];
        #pragma unroll
        for (int rr = 0; rr < 2; ++rr) { acc[rr][0]=0.f; acc[rr][1]=0.f; acc[rr][2]=0.f; acc[rr][3]=0.f; }
        const int Z0 = (ws_ * 36 + m) * HROWB + q * 16;   // H pixel row ws_*2, col m
        #pragma unroll
        for (int tap = 0; tap < 9; ++tap) {
            const int ky = tap / 3, kx = tap - ky * 3;
            #pragma unroll
            for (int ks = 0; ks < 2; ++ks) {
                const uint4* p = W4 + ((size_t)((40 + tap * 2 + ks) * 64) + lane) * 2;
                uint4 ah = p[0], al = p[1];
                #pragma unroll
                for (int rr = 0; rr < 2; ++rr) {
                    const char* zp = (const char*)Hs + Z0 + ((rr + ky) * 18 + kx) * HROWB + ks * 64;
                    uint2 u0 = *(const uint2*)zp;
                    uint2 u1 = *(const uint2*)(zp + 8);
                    uint4 Bv = make_uint4(u0.x, u0.y, u1.x, u1.y);
                    acc[rr] = __builtin_amdgcn_mfma_f32_16x16x32_bf16(as_bf8(ah), as_bf8(Bv), acc[rr], 0, 0, 0);
                    acc[rr] = __builtin_amdgcn_mfma_f32_16x16x32_bf16(as_bf8(al), as_bf8(Bv), acc[rr], 0, 0, 0);
                }
            }
        }
        // spline: lane(m,q) holds params w,h,d,shift for channel co=q at pixel (oy, ox=m) in regs 0..3
        float lad_sum = 0.0f;
        #pragma unroll
        for (int rr = 0; rr < 2; ++rr) {
            int gy = by * 16 + ws_ * 2 + rr, gx = bx * 16 + m;
            size_t xi = ((size_t)(b * 8 + 4 + q) * 256 + gy) * 256 + gx;
            float x = xv[rr];
            float pw = (acc[rr][0] + bzv[0]) * scl[0];
            float ph = (acc[rr][1] + bzv[1]) * scl[1];
            float pd = (acc[rr][2] + bzv[2]) * scl[2];
            float ps = (acc[rr][3] + bzv[3]) * scl[3];

            bool inside = (x > -0.5f) && (x < 0.5f);
            float xs = inside ? x : 0.0f;
            float wf = 1.0f / (1.0f + __expf(-pw)) * 0.998f + 0.001f;
            float hh = 1.0f / (1.0f + __expf(-ph)) * 0.998f + 0.001f;
            float dd = __expf(pd) * 0.999f + 0.001f;
            bool bin1 = (xs >= wf - 0.5f);
            float in_cw = bin1 ? (wf - 0.5f) : -0.5f;
            float in_w  = bin1 ? (1.0f - wf) : wf;
            float in_ch = bin1 ? (hh - 0.5f) : -0.5f;
            float in_h  = bin1 ? (1.0f - hh) : hh;
            float delta = in_h / in_w;
            float d0 = bin1 ? dd : 1.0f;
            float d1 = bin1 ? 1.0f : dd;
            float theta = (xs - in_cw) / in_w;
            float t1mt  = theta * (1.0f - theta);
            float denom = delta + (d0 + d1 - 2.0f * delta) * t1mt;
            float th2   = theta * theta;
            float ov    = in_ch + in_h * (delta * th2 + d0 * t1mt) / denom;
            float omt   = 1.0f - theta;
            float dnum  = delta * delta * (d1 * th2 + 2.0f * delta * t1mt + d0 * omt * omt);
            float lad   = __logf(dnum) - 2.0f * __logf(denom);
            ov  = fminf(fmaxf(ov, -0.5f), 0.5f);
            ov  = inside ? ov : x;
            lad = inside ? lad : 0.0f;
            outp[xi] = ov + ps;
            lad_sum += lad;
        }
        #pragma unroll
        for (int off = 32; off > 0; off >>= 1)
            lad_sum += __shfl_down(lad_sum, off, 64);
        if (lane == 0) red[ws_] = lad_sum;
    }
    __syncthreads();
    if (tid == 0) {
        float t = 0.0f;
        #pragma unroll
        for (int i = 0; i < 8; ++i) t += red[i];
        atomicAdd(&outp[OUT_TAIL + b], t);
    }
}

extern "C" void kernel_launch(void* const* d_in, const int* in_sizes, int n_in,
                              void* d_out, int out_size, void* d_ws, size_t ws_size,
                              hipStream_t stream) {
    const float* input  = (const float*)d_in[0];
    const float* logdet = (const float*)d_in[1];
    const float* ft     = (const float*)d_in[2];
    const float* w0 = (const float*)d_in[3];
    const float* b0 = (const float*)d_in[4];
    const float* w1 = (const float*)d_in[5];
    const float* b1 = (const float*)d_in[6];
    const float* w2 = (const float*)d_in[7];
    const float* b2 = (const float*)d_in[8];
    const float* w3 = (const float*)d_in[9];
    const float* b3 = (const float*)d_in[10];
    const float* w4 = (const float*)d_in[11];
    const float* b4 = (const float*)d_in[12];
    const float* wz = (const float*)d_in[13];
    const float* bz = (const float*)d_in[14];
    const float* logs = (const float*)d_in[15];
    float* outp = (float*)d_out;
    unsigned int* wsp = (unsigned int*)d_ws;

    prep_kernel<<<58, 64, 0, stream>>>(w0, w1, w2, w3, w4, wz, wsp);
    init_logdet_kernel<<<1, 64, 0, stream>>>(logdet, outp);
    fused_kernel<<<dim3(16, 16, 16), 512, 0, stream>>>(
        input, ft, b0, b1, b2, b3, b4, bz, logs, wsp, outp);
}

// Round 6
// 237.880 us; speedup vs baseline: 1.0793x; 1.0793x over previous
//
#include <hip/hip_runtime.h>
#include <math.h>

// Problem constants
#define OUT_TAIL (16*8*256*256)   // logdet lives after the output tensor
#define HSTR   68                 // bf16 elems per H row (64 + 4 pad) -> odd dword-pair stride, b64 conflict-free
#define HROWB  136                // bytes per H row
#define SSTRIDE 2176              // 16 rows * HROWB = strip stride in bytes
#define INSTR  408                // in_s per-channel stride (shorts)
#define WS2OFF 29696              // uint offset of K=16 layer-weight region in d_ws

typedef __bf16 bf8_t __attribute__((ext_vector_type(8)));
typedef float  f4_t  __attribute__((ext_vector_type(4)));

__device__ __forceinline__ unsigned rne16u_(float x) {
    unsigned u = __float_as_uint(x);
    return (u + 0x7fffu + ((u >> 16) & 1u)) >> 16;
}
#if __has_builtin(__builtin_amdgcn_cvt_pk_bf16_f32)
__device__ __forceinline__ unsigned pack2f(float a, float b) {
    typedef __bf16 bf2_t __attribute__((ext_vector_type(2)));
    bf2_t r = __builtin_amdgcn_cvt_pk_bf16_f32(a, b);
    return __builtin_bit_cast(unsigned, r);
}
#else
__device__ __forceinline__ unsigned pack2f(float a, float b) {
    unsigned r;
    asm("v_cvt_pk_bf16_f32 %0, %1, %2" : "=v"(r) : "v"(a), "v"(b));
    return r;
}
#endif
__device__ __forceinline__ bf8_t as_bf8(uint4 u) { return __builtin_bit_cast(bf8_t, u); }

// 16x16x16 bf16 MFMA wrapper (D/B layout identity enables register-resident chains)
#if __has_builtin(__builtin_amdgcn_mfma_f32_16x16x16_bf16)
typedef __bf16 bf4_t __attribute__((ext_vector_type(4)));
__device__ __forceinline__ f4_t mfma16(uint2 a, uint2 b, f4_t c) {
    return __builtin_amdgcn_mfma_f32_16x16x16_bf16(
        __builtin_bit_cast(bf4_t, a), __builtin_bit_cast(bf4_t, b), c, 0, 0, 0);
}
#else
typedef short s4_t __attribute__((ext_vector_type(4)));
__device__ __forceinline__ f4_t mfma16(uint2 a, uint2 b, f4_t c) {
    return __builtin_amdgcn_mfma_f32_16x16x16bf16_1k(
        __builtin_bit_cast(s4_t, a), __builtin_bit_cast(s4_t, b), c, 0, 0, 0);
}
#endif

// ---------------- prep ----------------
// Region A (f=0..57, uint4 hi|lo pairs): conv0 f=0..7 (Mt*2+ks, K=32), [8..39 unused legacy],
//   convz f=40..57 (tap*2+ks, K=32 hi/lo).
// Region B (at WS2OFF, uint2): layers1-4 K=16 A-frags, idx = (l*16 + Mt*4 + c)*64 + lane.
__global__ void prep_kernel(const float* __restrict__ w0, const float* __restrict__ w1,
                            const float* __restrict__ w2, const float* __restrict__ w3,
                            const float* __restrict__ w4, const float* __restrict__ wz,
                            unsigned int* __restrict__ ws) {
    int f = blockIdx.x;          // 0..121
    int lane = threadIdx.x;      // 0..63
    int m = lane & 15, qd = lane >> 4;
    if (f >= 58) {               // K=16 layer fragments (hi-only)
        int r = f - 58, l = r >> 4, fr = r & 15;
        int Mt = fr >> 2, c = fr & 3;
        const float* wp = (l == 0) ? w1 : (l == 1) ? w2 : (l == 2) ? w3 : w4;
        int co = Mt * 16 + m;
        float v0 = wp[co * 64 + c * 16 + qd * 4 + 0];
        float v1 = wp[co * 64 + c * 16 + qd * 4 + 1];
        float v2 = wp[co * 64 + c * 16 + qd * 4 + 2];
        float v3 = wp[co * 64 + c * 16 + qd * 4 + 3];
        unsigned int* p = ws + WS2OFF + (size_t)((l * 16 + Mt * 4 + c) * 64 + lane) * 2;
        p[0] = rne16u_(v0) | (rne16u_(v1) << 16);
        p[1] = rne16u_(v2) | (rne16u_(v3) << 16);
        return;
    }
    float vals[8];
    if (f < 8) {                 // conv0: K = ch*9+tap, 54 real
        int Mt = f >> 1, ks = f & 1;
        int c = Mt * 16 + m;
        for (int j = 0; j < 8; ++j) {
            int k = ks * 32 + qd * 8 + j;
            vals[j] = (k < 54) ? w0[c * 54 + k] : 0.0f;
        }
    } else if (f < 40) {         // legacy region, fill zeros
        for (int j = 0; j < 8; ++j) vals[j] = 0.0f;
    } else {                     // convz: per-tap
        int r = f - 40, tap = r >> 1, ks = r & 1;
        for (int j = 0; j < 8; ++j) {
            int k = ks * 32 + qd * 8 + j;
            vals[j] = wz[(m * 64 + k) * 9 + tap];
        }
    }
    unsigned int hi[4], lo[4];
    for (int i = 0; i < 4; ++i) {
        float a = vals[2 * i], c = vals[2 * i + 1];
        unsigned ha = rne16u_(a), hc = rne16u_(c);
        float ra = a - __uint_as_float(ha << 16);
        float rc = c - __uint_as_float(hc << 16);
        hi[i] = ha | (hc << 16);
        lo[i] = rne16u_(ra) | (rne16u_(rc) << 16);
    }
    unsigned int* p = ws + (size_t)(f * 64 + lane) * 8;
    for (int i = 0; i < 4; ++i) { p[i] = hi[i]; p[4 + i] = lo[i]; }
}

__global__ void init_logdet_kernel(const float* __restrict__ logdet, float* __restrict__ outp) {
    int i = threadIdx.x;
    if (i < 16) outp[OUT_TAIL + i] = logdet[i];
}

// ---------------- fused main kernel ----------------
// One block = one (batch, 16x16 tile). 256 threads = 4 waves.
// Wave 0 owns 6 strips (pixels 0..95), waves 1-3 own 5 strips each.
// Chain conv0 -> 4x(1x1) is fully register-resident (K=16 MFMA D/B layout identity);
// H hits LDS once (after layer 4) for convz's spatial stencil.
// LDS: Hs 45696 B + in_s 4928 B + red -> ~50.6 KB -> 3 blocks/CU
__global__ __launch_bounds__(256, 3)
void fused_kernel(const float* __restrict__ input, const float* __restrict__ ft,
                  const float* __restrict__ b0, const float* __restrict__ b1,
                  const float* __restrict__ b2, const float* __restrict__ b3,
                  const float* __restrict__ b4, const float* __restrict__ bz,
                  const float* __restrict__ logs, const unsigned int* __restrict__ wsp,
                  float* __restrict__ outp)
{
    __shared__ __align__(16) unsigned short Hs[336 * HSTR];
    __shared__ __align__(16) unsigned short in_s[2464];
    __shared__ float red[4];

    const int tid = threadIdx.x;
    const int bx = blockIdx.x, by = blockIdx.y, b = blockIdx.z;
    const int lane = tid & 63;
    const int ws_ = __builtin_amdgcn_readfirstlane(tid >> 6);   // wave id, scalar
    const int m = lane & 15, q = lane >> 4;
    const uint4* W4 = (const uint4*)wsp;
    const bool border = (bx == 0) | (bx == 15) | (by == 0) | (by == 15);

    // ---------------- stage input tile (bf16) + z1 fp32 passthrough ----------------
    {
        const int x0 = bx * 16 - 2, y0 = by * 16 - 2;
        int yy1 = tid / 20, xx1 = tid - yy1 * 20;
        int t2 = tid + 256;
        int yy2 = t2 / 20, xx2 = t2 - yy2 * 20;
        int gy1 = y0 + yy1, gx1 = x0 + xx1;
        int gy2 = y0 + yy2, gx2 = x0 + xx2;
        bool ok1 = ((unsigned)gy1 < 256u) && ((unsigned)gx1 < 256u);
        bool ok2 = ((unsigned)gy2 < 256u) && ((unsigned)gx2 < 256u);
        #pragma unroll
        for (int c = 0; c < 6; ++c) {
            const float* src = (c < 4) ? input + (size_t)(b * 8 + c) * 65536
                                       : ft + (size_t)(b * 2 + (c - 4)) * 65536;
            float v1 = ok1 ? src[gy1 * 256 + gx1] : 0.0f;
            in_s[c * INSTR + yy1 * 20 + xx1] = (unsigned short)(pack2f(v1, 0.0f) & 0xffffu);
            if (tid < 144) {
                float v2 = ok2 ? src[gy2 * 256 + gx2] : 0.0f;
                in_s[c * INSTR + yy2 * 20 + xx2] = (unsigned short)(pack2f(v2, 0.0f) & 0xffffu);
            }
        }
        // z1 exact fp32 passthrough: 4 floats per thread
        int c = tid >> 6;
        int rem = (tid & 63) * 4;
        int oy = rem >> 4, ox = rem & 15;
        size_t o = ((size_t)(b * 8 + c) * 256 + by * 16 + oy) * 256 + bx * 16 + ox;
        *(float4*)&outp[o] = *(const float4*)&input[o];
    }
    __syncthreads();

    const int nstrip = (ws_ == 0) ? 6 : 5;
    const int pbase  = (ws_ == 0) ? 0 : (80 * ws_ + 16);
    const int pix0   = pbase + m;
    const int A0 = pix0 * HROWB + q * 16;   // convz H read base (bytes)
    const int W0 = pix0 * HROWB + q * 8;    // H write base (bytes); + s*SSTRIDE + Mt*32

    // Register-resident activation chain: Bc[s][c] = packed bf16 channels c*16+4q..+3, pixel pix0+16s
    uint2 Bc[6][4];

    // ---------------- conv0 3x3 (6->64) via K=32 MFMA (hi-only), im2col gather ----------------
    {
        int koffB[16];
        #pragma unroll
        for (int ks = 0; ks < 2; ++ks)
            #pragma unroll
            for (int j = 0; j < 8; ++j) {
                int k = ks * 32 + q * 8 + j;
                int ch = k / 9, tap = k - ch * 9;
                int ky = tap / 3, kx = tap - ky * 3;
                koffB[ks * 8 + j] = (k < 54) ? (ch * INSTR + ky * 20 + kx) * 2 : 0;
            }
        uint4 Ah[8];
        #pragma unroll
        for (int f = 0; f < 8; ++f)
            Ah[f] = W4[((size_t)(f * 64) + lane) * 2];
        f4_t bv4[4];
        #pragma unroll
        for (int Mt = 0; Mt < 4; ++Mt)
            #pragma unroll
            for (int r = 0; r < 4; ++r) bv4[Mt][r] = b0[Mt * 16 + q * 4 + r];

        int cpy = (pix0 * 1821) >> 15;      // pix0 / 18 (exact for 0..335)
        int cpx = pix0 - cpy * 18;
        #pragma unroll
        for (int s = 0; s < 6; ++s) {
            if (s < nstrip) {
                int ib = (cpy * 20 + cpx) * 2;
                unsigned e[16];
                #pragma unroll
                for (int i = 0; i < 16; ++i)
                    e[i] = *(const unsigned short*)((const char*)in_s + ib + koffB[i]);
                uint4 B0 = make_uint4(e[0] | (e[1] << 16), e[2] | (e[3] << 16),
                                      e[4] | (e[5] << 16), e[6] | (e[7] << 16));
                uint4 B1 = make_uint4(e[8] | (e[9] << 16), e[10] | (e[11] << 16),
                                      e[12] | (e[13] << 16), e[14] | (e[15] << 16));
                #pragma unroll
                for (int Mt = 0; Mt < 4; ++Mt) {
                    f4_t a = __builtin_amdgcn_mfma_f32_16x16x32_bf16(as_bf8(Ah[Mt*2+0]), as_bf8(B0), bv4[Mt], 0, 0, 0);
                    a = __builtin_amdgcn_mfma_f32_16x16x32_bf16(as_bf8(Ah[Mt*2+1]), as_bf8(B1), a, 0, 0, 0);
                    Bc[s][Mt].x = pack2f(fmaxf(a[0], 0.f), fmaxf(a[1], 0.f));
                    Bc[s][Mt].y = pack2f(fmaxf(a[2], 0.f), fmaxf(a[3], 0.f));
                }
            }
            cpx += 16;
            if (cpx >= 18) { cpx -= 18; cpy += 1; }
        }
    }

    // ---------------- 4x (1x1 conv 64->64 + ReLU) via K=16 MFMA, all in registers ----------------
    #pragma unroll 1
    for (int l = 0; l < 4; ++l) {
        const float* bl = (l == 0) ? b1 : (l == 1) ? b2 : (l == 2) ? b3 : b4;
        uint2 Aw[16];
        #pragma unroll
        for (int f = 0; f < 16; ++f)
            Aw[f] = *(const uint2*)(wsp + WS2OFF + (size_t)((l * 16 + f) * 64 + lane) * 2);
        f4_t bv4[4];
        #pragma unroll
        for (int Mt = 0; Mt < 4; ++Mt)
            #pragma unroll
            for (int r = 0; r < 4; ++r) bv4[Mt][r] = bl[Mt * 16 + q * 4 + r];

        #pragma unroll
        for (int s = 0; s < 6; ++s) {
            if (s < nstrip) {
                f4_t acc[4];
                #pragma unroll
                for (int Mt = 0; Mt < 4; ++Mt) {
                    f4_t a = bv4[Mt];
                    #pragma unroll
                    for (int c = 0; c < 4; ++c)
                        a = mfma16(Aw[Mt * 4 + c], Bc[s][c], a);
                    acc[Mt] = a;
                }
                #pragma unroll
                for (int Mt = 0; Mt < 4; ++Mt) {
                    Bc[s][Mt].x = pack2f(fmaxf(acc[Mt][0], 0.f), fmaxf(acc[Mt][1], 0.f));
                    Bc[s][Mt].y = pack2f(fmaxf(acc[Mt][2], 0.f), fmaxf(acc[Mt][3], 0.f));
                }
            }
        }
    }

    // ---------------- write H to LDS (once) + border zeroing ----------------
    #pragma unroll
    for (int s = 0; s < 6; ++s) {
        if (s < nstrip) {
            #pragma unroll
            for (int Mt = 0; Mt < 4; ++Mt)
                *(uint2*)((char*)Hs + W0 + s * SSTRIDE + Mt * 32) = Bc[s][Mt];
        }
    }
    if (border) {
        #pragma unroll
        for (int s = 0; s < 6; ++s) {
            if (s < nstrip) {
                int pixs = pix0 + 16 * s;
                int pys = (pixs * 1821) >> 15;
                int pxs = pixs - pys * 18;
                int gy = by * 16 - 1 + pys, gx = bx * 16 - 1 + pxs;
                if (!(((unsigned)gy < 256u) && ((unsigned)gx < 256u))) {
                    char* zp = (char*)Hs + A0 + s * SSTRIDE;
                    *(uint2*)(zp)      = make_uint2(0, 0);
                    *(uint2*)(zp + 8)  = make_uint2(0, 0);
                    *(uint2*)(zp + 64) = make_uint2(0, 0);
                    *(uint2*)(zp + 72) = make_uint2(0, 0);
                }
            }
        }
    }
    __syncthreads();

    // ---------------- convz 3x3 (64->16) via K=32 MFMA (hi+lo) + RQ spline ----------------
    {
        float xv[4];
        #pragma unroll
        for (int rr = 0; rr < 4; ++rr) {
            int gy = by * 16 + ws_ * 4 + rr;
            xv[rr] = input[((size_t)(b * 8 + 4 + q) * 256 + gy) * 256 + bx * 16 + m];
        }
        float bzv[4], scl[4];
        #pragma unroll
        for (int r = 0; r < 4; ++r) {
            int c = q * 4 + r;
            bzv[r] = bz[c];
            scl[r] = __expf(3.0f * logs[c]);
        }
        f4_t acc[4];
        #pragma unroll
        for (int rr = 0; rr < 4; ++rr) { acc[rr][0]=0.f; acc[rr][1]=0.f; acc[rr][2]=0.f; acc[rr][3]=0.f; }
        const int Z0 = (ws_ * 72 + m) * HROWB + q * 16;
        #pragma unroll
        for (int tap = 0; tap < 9; ++tap) {
            const int ky = tap / 3, kx = tap - ky * 3;
            #pragma unroll
            for (int ks = 0; ks < 2; ++ks) {
                const uint4* p = W4 + ((size_t)((40 + tap * 2 + ks) * 64) + lane) * 2;
                uint4 ah = p[0], al = p[1];
                #pragma unroll
                for (int rr = 0; rr < 4; ++rr) {
                    const char* zp = (const char*)Hs + Z0 + ((rr + ky) * 18 + kx) * HROWB + ks * 64;
                    uint2 u0 = *(const uint2*)zp;
                    uint2 u1 = *(const uint2*)(zp + 8);
                    uint4 Bv = make_uint4(u0.x, u0.y, u1.x, u1.y);
                    acc[rr] = __builtin_amdgcn_mfma_f32_16x16x32_bf16(as_bf8(ah), as_bf8(Bv), acc[rr], 0, 0, 0);
                    acc[rr] = __builtin_amdgcn_mfma_f32_16x16x32_bf16(as_bf8(al), as_bf8(Bv), acc[rr], 0, 0, 0);
                }
            }
        }
        float lad_sum = 0.0f;
        #pragma unroll
        for (int rr = 0; rr < 4; ++rr) {
            int gy = by * 16 + ws_ * 4 + rr, gx = bx * 16 + m;
            size_t xi = ((size_t)(b * 8 + 4 + q) * 256 + gy) * 256 + gx;
            float x = xv[rr];
            float pw = (acc[rr][0] + bzv[0]) * scl[0];
            float ph = (acc[rr][1] + bzv[1]) * scl[1];
            float pd = (acc[rr][2] + bzv[2]) * scl[2];
            float ps = (acc[rr][3] + bzv[3]) * scl[3];

            bool inside = (x > -0.5f) && (x < 0.5f);
            float xs = inside ? x : 0.0f;
            float wf = 1.0f / (1.0f + __expf(-pw)) * 0.998f + 0.001f;
            float hh = 1.0f / (1.0f + __expf(-ph)) * 0.998f + 0.001f;
            float dd = __expf(pd) * 0.999f + 0.001f;
            bool bin1 = (xs >= wf - 0.5f);
            float in_cw = bin1 ? (wf - 0.5f) : -0.5f;
            float in_w  = bin1 ? (1.0f - wf) : wf;
            float in_ch = bin1 ? (hh - 0.5f) : -0.5f;
            float in_h  = bin1 ? (1.0f - hh) : hh;
            float delta = in_h / in_w;
            float d0 = bin1 ? dd : 1.0f;
            float d1 = bin1 ? 1.0f : dd;
            float theta = (xs - in_cw) / in_w;
            float t1mt  = theta * (1.0f - theta);
            float denom = delta + (d0 + d1 - 2.0f * delta) * t1mt;
            float th2   = theta * theta;
            float ov    = in_ch + in_h * (delta * th2 + d0 * t1mt) / denom;
            float omt   = 1.0f - theta;
            float dnum  = delta * delta * (d1 * th2 + 2.0f * delta * t1mt + d0 * omt * omt);
            float lad   = __logf(dnum) - 2.0f * __logf(denom);
            ov  = fminf(fmaxf(ov, -0.5f), 0.5f);
            ov  = inside ? ov : x;
            lad = inside ? lad : 0.0f;
            outp[xi] = ov + ps;
            lad_sum += lad;
        }
        #pragma unroll
        for (int off = 32; off > 0; off >>= 1)
            lad_sum += __shfl_down(lad_sum, off, 64);
        if (lane == 0) red[ws_] = lad_sum;
    }
    __syncthreads();
    if (tid == 0)
        atomicAdd(&outp[OUT_TAIL + b], red[0] + red[1] + red[2] + red[3]);
}

extern "C" void kernel_launch(void* const* d_in, const int* in_sizes, int n_in,
                              void* d_out, int out_size, void* d_ws, size_t ws_size,
                              hipStream_t stream) {
    const float* input  = (const float*)d_in[0];
    const float* logdet = (const float*)d_in[1];
    const float* ft     = (const float*)d_in[2];
    const float* w0 = (const float*)d_in[3];
    const float* b0 = (const float*)d_in[4];
    const float* w1 = (const float*)d_in[5];
    const float* b1 = (const float*)d_in[6];
    const float* w2 = (const float*)d_in[7];
    const float* b2 = (const float*)d_in[8];
    const float* w3 = (const float*)d_in[9];
    const float* b3 = (const float*)d_in[10];
    const float* w4 = (const float*)d_in[11];
    const float* b4 = (const float*)d_in[12];
    const float* wz = (const float*)d_in[13];
    const float* bz = (const float*)d_in[14];
    const float* logs = (const float*)d_in[15];
    float* outp = (float*)d_out;
    unsigned int* wsp = (unsigned int*)d_ws;

    prep_kernel<<<122, 64, 0, stream>>>(w0, w1, w2, w3, w4, wz, wsp);
    init_logdet_kernel<<<1, 64, 0, stream>>>(logdet, outp);
    fused_kernel<<<dim3(16, 16, 16), 256, 0, stream>>>(
        input, ft, b0, b1, b2, b3, b4, bz, logs, wsp, outp);
}

// Round 7
// 228.143 us; speedup vs baseline: 1.1254x; 1.0427x over previous
//
#include <hip/hip_runtime.h>
#include <math.h>

// Problem constants
#define OUT_TAIL (16*8*256*256)   // logdet lives after the output tensor
#define HSTR   68                 // bf16 elems per H row (64 + 4 pad) -> odd dword-pair stride, b64 conflict-free
#define HROWB  136                // bytes per H row
#define SSTRIDE 2176              // 16 rows * HROWB = strip stride in bytes
#define INSTR  408                // in_s per-channel stride (shorts)

typedef __bf16 bf8_t __attribute__((ext_vector_type(8)));
typedef float  f4_t  __attribute__((ext_vector_type(4)));

__device__ __forceinline__ unsigned rne16u_(float x) {
    unsigned u = __float_as_uint(x);
    return (u + 0x7fffu + ((u >> 16) & 1u)) >> 16;
}
#if __has_builtin(__builtin_amdgcn_cvt_pk_bf16_f32)
__device__ __forceinline__ unsigned pack2f(float a, float b) {
    typedef __bf16 bf2_t __attribute__((ext_vector_type(2)));
    bf2_t r = __builtin_amdgcn_cvt_pk_bf16_f32(a, b);
    return __builtin_bit_cast(unsigned, r);
}
#else
__device__ __forceinline__ unsigned pack2f(float a, float b) {
    unsigned r;
    asm("v_cvt_pk_bf16_f32 %0, %1, %2" : "=v"(r) : "v"(a), "v"(b));
    return r;
}
#endif
__device__ __forceinline__ bf8_t as_bf8(uint4 u) { return __builtin_bit_cast(bf8_t, u); }
__device__ __forceinline__ f4_t mfma32(uint4 a, uint4 b, f4_t c) {
    return __builtin_amdgcn_mfma_f32_16x16x32_bf16(as_bf8(a), as_bf8(b), c, 0, 0, 0);
}

// ---------------- prep: split weights into hi/lo bf16 MFMA A-fragments ----------------
// frag ids: conv0: 0..7 (Mt*2+ks) ; layers1-4: 8+l*8+Mt*2+ks ; convz: 40+tap*2+ks
// record: [frag][lane][hi u32 x4 | lo u32 x4]
__global__ void prep_kernel(const float* __restrict__ w0, const float* __restrict__ w1,
                            const float* __restrict__ w2, const float* __restrict__ w3,
                            const float* __restrict__ w4, const float* __restrict__ wz,
                            unsigned int* __restrict__ ws) {
    int f = blockIdx.x;          // 0..57
    int lane = threadIdx.x;      // 0..63
    int m = lane & 15, qd = lane >> 4;
    float vals[8];
    if (f < 8) {                 // conv0: K = ch*9+tap, 54 real
        int Mt = f >> 1, ks = f & 1;
        int c = Mt * 16 + m;
        for (int j = 0; j < 8; ++j) {
            int k = ks * 32 + qd * 8 + j;
            vals[j] = (k < 54) ? w0[c * 54 + k] : 0.0f;
        }
    } else if (f < 40) {         // 1x1 layers
        int r = f - 8, l = r >> 3, fr = r & 7;
        int Mt = fr >> 1, ks = fr & 1;
        const float* wp = (l == 0) ? w1 : (l == 1) ? w2 : (l == 2) ? w3 : w4;
        int c = Mt * 16 + m;
        for (int j = 0; j < 8; ++j) vals[j] = wp[c * 64 + ks * 32 + qd * 8 + j];
    } else {                     // convz: per-tap
        int r = f - 40, tap = r >> 1, ks = r & 1;
        for (int j = 0; j < 8; ++j) {
            int k = ks * 32 + qd * 8 + j;
            vals[j] = wz[(m * 64 + k) * 9 + tap];
        }
    }
    unsigned int hi[4], lo[4];
    for (int i = 0; i < 4; ++i) {
        float a = vals[2 * i], c = vals[2 * i + 1];
        unsigned ha = rne16u_(a), hc = rne16u_(c);
        float ra = a - __uint_as_float(ha << 16);
        float rc = c - __uint_as_float(hc << 16);
        hi[i] = ha | (hc << 16);
        lo[i] = rne16u_(ra) | (rne16u_(rc) << 16);
    }
    unsigned int* p = ws + (size_t)(f * 64 + lane) * 8;
    for (int i = 0; i < 4; ++i) { p[i] = hi[i]; p[4 + i] = lo[i]; }
}

__global__ void init_logdet_kernel(const float* __restrict__ logdet, float* __restrict__ outp) {
    int i = threadIdx.x;
    if (i < 16) outp[OUT_TAIL + i] = logdet[i];
}

// ---------------- fused main kernel ----------------
// One block = one (batch, 16x16 tile). 256 threads = 4 waves.
// Wave 0 owns pixels 0..95 (6 strips), waves 1-3 own 5 strips each (80 px).
// Strips 0..4 are unconditional straight-line code; wave-0 strip 5 is a scalar-guarded tail.
// Each layer: phase R (all 20 b64 H-reads) -> prefetch next-layer weights -> phase M (MFMA/pack/write).
// LDS: Hs 45696 B + in_s 4928 B + red -> ~50.6 KB -> 3 blocks/CU
__global__ __launch_bounds__(256, 3)
void fused_kernel(const float* __restrict__ input, const float* __restrict__ ft,
                  const float* __restrict__ b0, const float* __restrict__ b1,
                  const float* __restrict__ b2, const float* __restrict__ b3,
                  const float* __restrict__ b4, const float* __restrict__ bz,
                  const float* __restrict__ logs, const unsigned int* __restrict__ wsp,
                  float* __restrict__ outp)
{
    __shared__ __align__(16) unsigned short Hs[336 * HSTR];
    __shared__ __align__(16) unsigned short in_s[2464];
    __shared__ float red[4];

    const int tid = threadIdx.x;
    const int bx = blockIdx.x, by = blockIdx.y, b = blockIdx.z;
    const int lane = tid & 63;
    const int ws_ = __builtin_amdgcn_readfirstlane(tid >> 6);   // wave id, scalar
    const int m = lane & 15, q = lane >> 4;
    const uint4* W4 = (const uint4*)wsp;
    const bool border = (bx == 0) | (bx == 15) | (by == 0) | (by == 15);

    // ---------------- stage input tile (bf16) + z1 fp32 passthrough ----------------
    {
        const int x0 = bx * 16 - 2, y0 = by * 16 - 2;
        int yy1 = tid / 20, xx1 = tid - yy1 * 20;
        int t2 = tid + 256;
        int yy2 = t2 / 20, xx2 = t2 - yy2 * 20;
        int gy1 = y0 + yy1, gx1 = x0 + xx1;
        int gy2 = y0 + yy2, gx2 = x0 + xx2;
        bool ok1 = ((unsigned)gy1 < 256u) && ((unsigned)gx1 < 256u);
        bool ok2 = ((unsigned)gy2 < 256u) && ((unsigned)gx2 < 256u);
        #pragma unroll
        for (int c = 0; c < 6; ++c) {
            const float* src = (c < 4) ? input + (size_t)(b * 8 + c) * 65536
                                       : ft + (size_t)(b * 2 + (c - 4)) * 65536;
            float v1 = ok1 ? src[gy1 * 256 + gx1] : 0.0f;
            in_s[c * INSTR + yy1 * 20 + xx1] = (unsigned short)(pack2f(v1, 0.0f) & 0xffffu);
            if (tid < 144) {
                float v2 = ok2 ? src[gy2 * 256 + gx2] : 0.0f;
                in_s[c * INSTR + yy2 * 20 + xx2] = (unsigned short)(pack2f(v2, 0.0f) & 0xffffu);
            }
        }
        // z1 exact fp32 passthrough: 4 floats per thread
        int c = tid >> 6;
        int rem = (tid & 63) * 4;
        int oy = rem >> 4, ox = rem & 15;
        size_t o = ((size_t)(b * 8 + c) * 256 + by * 16 + oy) * 256 + bx * 16 + ox;
        *(float4*)&outp[o] = *(const float4*)&input[o];
    }
    __syncthreads();

    const int pbase = (ws_ == 0) ? 0 : (80 * ws_ + 16);
    const int pix0  = pbase + m;
    const int A0 = pix0 * HROWB + q * 16;   // H B-read base (bytes)
    const int W0 = pix0 * HROWB + q * 8;    // H write base (bytes); + s*SSTRIDE + Mt*32

    // strip base offsets into in_s (bytes)
    int ibs[6];
    {
        int cpy = (pix0 * 1821) >> 15;      // pix0 / 18 (exact for 0..351)
        int cpx = pix0 - cpy * 18;
        #pragma unroll
        for (int s = 0; s < 6; ++s) {
            ibs[s] = (cpy * 20 + cpx) * 2;
            cpx += 16;
            if (cpx >= 18) { cpx -= 18; cpy += 1; }
        }
    }

    uint4 Aw[2][8];      // double-buffered layer weights
    f4_t  bvl[2][4];     // double-buffered layer biases
    uint4 czA[2], czL[2];// convz tap weights (hi/lo), current tap

    // ---------------- conv0 3x3 (6->64) via K=32 MFMA (hi-only), 1-deep gather pipeline ----------------
    {
        int koffB[16];
        #pragma unroll
        for (int ks = 0; ks < 2; ++ks)
            #pragma unroll
            for (int j = 0; j < 8; ++j) {
                int k = ks * 32 + q * 8 + j;
                int ch = k / 9, tap = k - ch * 9;
                int ky = tap / 3, kx = tap - ky * 3;
                koffB[ks * 8 + j] = (k < 54) ? (ch * INSTR + ky * 20 + kx) * 2 : 0;
            }
        uint4 Ah0[8];
        #pragma unroll
        for (int f = 0; f < 8; ++f)
            Ah0[f] = W4[((size_t)(f * 64) + lane) * 2];
        f4_t bc0[4];
        #pragma unroll
        for (int Mt = 0; Mt < 4; ++Mt)
            bc0[Mt] = *(const f4_t*)(b0 + Mt * 16 + q * 4);

        #define GATHER(ib, B0, B1) {                                            \
            unsigned e[16];                                                     \
            _Pragma("unroll")                                                   \
            for (int i = 0; i < 16; ++i)                                        \
                e[i] = *(const unsigned short*)((const char*)in_s + (ib) + koffB[i]); \
            B0 = make_uint4(e[0]|(e[1]<<16), e[2]|(e[3]<<16),                   \
                            e[4]|(e[5]<<16), e[6]|(e[7]<<16));                  \
            B1 = make_uint4(e[8]|(e[9]<<16), e[10]|(e[11]<<16),                 \
                            e[12]|(e[13]<<16), e[14]|(e[15]<<16));              \
        }

        uint4 Gc0, Gc1, Gn0, Gn1;
        GATHER(ibs[0], Gc0, Gc1);
        #pragma unroll
        for (int s = 0; s < 5; ++s) {
            if (s == 0) {   // prefetch layer-0 weights+biases behind the first gather
                #pragma unroll
                for (int f = 0; f < 8; ++f)
                    Aw[0][f] = W4[((size_t)((8 + f) * 64) + lane) * 2];
                #pragma unroll
                for (int Mt = 0; Mt < 4; ++Mt)
                    bvl[0][Mt] = *(const f4_t*)(b1 + Mt * 16 + q * 4);
            }
            if ((s < 4) || (ws_ == 0)) GATHER(ibs[s + 1], Gn0, Gn1);
            #pragma unroll
            for (int Mt = 0; Mt < 4; ++Mt) {
                f4_t a = mfma32(Ah0[2*Mt], Gc0, bc0[Mt]);
                a = mfma32(Ah0[2*Mt+1], Gc1, a);
                uint2 pr;
                pr.x = pack2f(fmaxf(a[0], 0.f), fmaxf(a[1], 0.f));
                pr.y = pack2f(fmaxf(a[2], 0.f), fmaxf(a[3], 0.f));
                *(uint2*)((char*)Hs + W0 + s * SSTRIDE + Mt * 32) = pr;
            }
            Gc0 = Gn0; Gc1 = Gn1;
        }
        if (ws_ == 0) {   // tail strip 5
            #pragma unroll
            for (int Mt = 0; Mt < 4; ++Mt) {
                f4_t a = mfma32(Ah0[2*Mt], Gc0, bc0[Mt]);
                a = mfma32(Ah0[2*Mt+1], Gc1, a);
                uint2 pr;
                pr.x = pack2f(fmaxf(a[0], 0.f), fmaxf(a[1], 0.f));
                pr.y = pack2f(fmaxf(a[2], 0.f), fmaxf(a[3], 0.f));
                *(uint2*)((char*)Hs + W0 + 5 * SSTRIDE + Mt * 32) = pr;
            }
        }
        #undef GATHER
    }

    // ---------------- 4x (1x1 conv 64->64 + ReLU), phase-split, weight prefetch ----------------
    #pragma unroll
    for (int l = 0; l < 4; ++l) {
        const int cur = l & 1, nxt = cur ^ 1;
        // phase R: all H reads for strips 0..4
        uint2 Bsl[5][4];
        #pragma unroll
        for (int s = 0; s < 5; ++s) {
            const char* rp = (const char*)Hs + A0 + s * SSTRIDE;
            Bsl[s][0] = *(const uint2*)(rp);
            Bsl[s][1] = *(const uint2*)(rp + 8);
            Bsl[s][2] = *(const uint2*)(rp + 64);
            Bsl[s][3] = *(const uint2*)(rp + 72);
        }
        // prefetch next-layer weights+biases (or convz tap-0 weights at l=3)
        if (l < 3) {
            #pragma unroll
            for (int f = 0; f < 8; ++f)
                Aw[nxt][f] = W4[((size_t)((8 + (l + 1) * 8 + f) * 64) + lane) * 2];
            const float* bn = (l == 0) ? b2 : (l == 1) ? b3 : b4;
            #pragma unroll
            for (int Mt = 0; Mt < 4; ++Mt)
                bvl[nxt][Mt] = *(const f4_t*)(bn + Mt * 16 + q * 4);
        } else {
            #pragma unroll
            for (int ks = 0; ks < 2; ++ks) {
                const uint4* p = W4 + ((size_t)((40 + ks) * 64) + lane) * 2;
                czA[ks] = p[0]; czL[ks] = p[1];
            }
        }
        // phase M: MFMA + pack + write
        #pragma unroll
        for (int s = 0; s < 5; ++s) {
            uint4 B0 = make_uint4(Bsl[s][0].x, Bsl[s][0].y, Bsl[s][1].x, Bsl[s][1].y);
            uint4 B1 = make_uint4(Bsl[s][2].x, Bsl[s][2].y, Bsl[s][3].x, Bsl[s][3].y);
            #pragma unroll
            for (int Mt = 0; Mt < 4; ++Mt) {
                f4_t a = mfma32(Aw[cur][2*Mt], B0, bvl[cur][Mt]);
                a = mfma32(Aw[cur][2*Mt+1], B1, a);
                uint2 pr;
                pr.x = pack2f(fmaxf(a[0], 0.f), fmaxf(a[1], 0.f));
                pr.y = pack2f(fmaxf(a[2], 0.f), fmaxf(a[3], 0.f));
                *(uint2*)((char*)Hs + W0 + s * SSTRIDE + Mt * 32) = pr;
            }
        }
        if (ws_ == 0) {   // tail strip 5
            const char* rp = (const char*)Hs + A0 + 5 * SSTRIDE;
            uint2 a0 = *(const uint2*)(rp);
            uint2 a1 = *(const uint2*)(rp + 8);
            uint2 a2 = *(const uint2*)(rp + 64);
            uint2 a3 = *(const uint2*)(rp + 72);
            uint4 B0 = make_uint4(a0.x, a0.y, a1.x, a1.y);
            uint4 B1 = make_uint4(a2.x, a2.y, a3.x, a3.y);
            #pragma unroll
            for (int Mt = 0; Mt < 4; ++Mt) {
                f4_t a = mfma32(Aw[cur][2*Mt], B0, bvl[cur][Mt]);
                a = mfma32(Aw[cur][2*Mt+1], B1, a);
                uint2 pr;
                pr.x = pack2f(fmaxf(a[0], 0.f), fmaxf(a[1], 0.f));
                pr.y = pack2f(fmaxf(a[2], 0.f), fmaxf(a[3], 0.f));
                *(uint2*)((char*)Hs + W0 + 5 * SSTRIDE + Mt * 32) = pr;
            }
        }
    }

    // ---------------- border blocks: zero H rows outside the image (convz zero-pad) ----------------
    if (border) {
        #pragma unroll
        for (int s = 0; s < 6; ++s) {
            if (s < 5 || ws_ == 0) {
                int pixs = pix0 + 16 * s;
                int pys = (pixs * 1821) >> 15;
                int pxs = pixs - pys * 18;
                int gy = by * 16 - 1 + pys, gx = bx * 16 - 1 + pxs;
                if (!(((unsigned)gy < 256u) && ((unsigned)gx < 256u))) {
                    char* zp = (char*)Hs + A0 + s * SSTRIDE;
                    *(uint2*)(zp)      = make_uint2(0, 0);
                    *(uint2*)(zp + 8)  = make_uint2(0, 0);
                    *(uint2*)(zp + 64) = make_uint2(0, 0);
                    *(uint2*)(zp + 72) = make_uint2(0, 0);
                }
            }
        }
    }

    // prefetch spline inputs + constants before the barrier (global, Hs-independent)
    float xv[4], bzv[4], scl[4];
    #pragma unroll
    for (int rr = 0; rr < 4; ++rr) {
        int gy = by * 16 + ws_ * 4 + rr;
        xv[rr] = input[((size_t)(b * 8 + 4 + q) * 256 + gy) * 256 + bx * 16 + m];
    }
    #pragma unroll
    for (int r = 0; r < 4; ++r) {
        int c = q * 4 + r;
        bzv[r] = bz[c];
        scl[r] = __expf(3.0f * logs[c]);
    }
    __syncthreads();

    // ---------------- convz 3x3 (64->16) via K=32 MFMA (hi+lo), tap-ahead weight prefetch ----------------
    {
        f4_t acc[4];
        #pragma unroll
        for (int rr = 0; rr < 4; ++rr) { acc[rr][0]=0.f; acc[rr][1]=0.f; acc[rr][2]=0.f; acc[rr][3]=0.f; }
        const int Z0 = (ws_ * 72 + m) * HROWB + q * 16;
        #pragma unroll
        for (int tap = 0; tap < 9; ++tap) {
            uint4 nA[2], nL[2];
            if (tap < 8) {
                #pragma unroll
                for (int ks = 0; ks < 2; ++ks) {
                    const uint4* p = W4 + ((size_t)((40 + (tap + 1) * 2 + ks) * 64) + lane) * 2;
                    nA[ks] = p[0]; nL[ks] = p[1];
                }
            }
            const int ky = tap / 3, kx = tap - ky * 3;
            #pragma unroll
            for (int ks = 0; ks < 2; ++ks) {
                #pragma unroll
                for (int rr = 0; rr < 4; ++rr) {
                    const char* zp = (const char*)Hs + Z0 + ((rr + ky) * 18 + kx) * HROWB + ks * 64;
                    uint2 u0 = *(const uint2*)zp;
                    uint2 u1 = *(const uint2*)(zp + 8);
                    uint4 Bv = make_uint4(u0.x, u0.y, u1.x, u1.y);
                    acc[rr] = mfma32(czA[ks], Bv, acc[rr]);
                    acc[rr] = mfma32(czL[ks], Bv, acc[rr]);
                }
            }
            czA[0] = nA[0]; czA[1] = nA[1];
            czL[0] = nL[0]; czL[1] = nL[1];
        }
        // spline: lane(m,q) holds params w,h,d,shift for channel co=q at pixel (oy, ox=m) in regs 0..3
        float lad_sum = 0.0f;
        #pragma unroll
        for (int rr = 0; rr < 4; ++rr) {
            int gy = by * 16 + ws_ * 4 + rr, gx = bx * 16 + m;
            size_t xi = ((size_t)(b * 8 + 4 + q) * 256 + gy) * 256 + gx;
            float x = xv[rr];
            float pw = (acc[rr][0] + bzv[0]) * scl[0];
            float ph = (acc[rr][1] + bzv[1]) * scl[1];
            float pd = (acc[rr][2] + bzv[2]) * scl[2];
            float ps = (acc[rr][3] + bzv[3]) * scl[3];

            bool inside = (x > -0.5f) && (x < 0.5f);
            float xs = inside ? x : 0.0f;
            float wf = 1.0f / (1.0f + __expf(-pw)) * 0.998f + 0.001f;
            float hh = 1.0f / (1.0f + __expf(-ph)) * 0.998f + 0.001f;
            float dd = __expf(pd) * 0.999f + 0.001f;
            bool bin1 = (xs >= wf - 0.5f);
            float in_cw = bin1 ? (wf - 0.5f) : -0.5f;
            float in_w  = bin1 ? (1.0f - wf) : wf;
            float in_ch = bin1 ? (hh - 0.5f) : -0.5f;
            float in_h  = bin1 ? (1.0f - hh) : hh;
            float delta = in_h / in_w;
            float d0 = bin1 ? dd : 1.0f;
            float d1 = bin1 ? 1.0f : dd;
            float theta = (xs - in_cw) / in_w;
            float t1mt  = theta * (1.0f - theta);
            float denom = delta + (d0 + d1 - 2.0f * delta) * t1mt;
            float th2   = theta * theta;
            float ov    = in_ch + in_h * (delta * th2 + d0 * t1mt) / denom;
            float omt   = 1.0f - theta;
            float dnum  = delta * delta * (d1 * th2 + 2.0f * delta * t1mt + d0 * omt * omt);
            float lad   = __logf(dnum) - 2.0f * __logf(denom);
            ov  = fminf(fmaxf(ov, -0.5f), 0.5f);
            ov  = inside ? ov : x;
            lad = inside ? lad : 0.0f;
            outp[xi] = ov + ps;
            lad_sum += lad;
        }
        #pragma unroll
        for (int off = 32; off > 0; off >>= 1)
            lad_sum += __shfl_down(lad_sum, off, 64);
        if (lane == 0) red[ws_] = lad_sum;
    }
    __syncthreads();
    if (tid == 0)
        atomicAdd(&outp[OUT_TAIL + b], red[0] + red[1] + red[2] + red[3]);
}

extern "C" void kernel_launch(void* const* d_in, const int* in_sizes, int n_in,
                              void* d_out, int out_size, void* d_ws, size_t ws_size,
                              hipStream_t stream) {
    const float* input  = (const float*)d_in[0];
    const float* logdet = (const float*)d_in[1];
    const float* ft     = (const float*)d_in[2];
    const float* w0 = (const float*)d_in[3];
    const float* b0 = (const float*)d_in[4];
    const float* w1 = (const float*)d_in[5];
    const float* b1 = (const float*)d_in[6];
    const float* w2 = (const float*)d_in[7];
    const float* b2 = (const float*)d_in[8];
    const float* w3 = (const float*)d_in[9];
    const float* b3 = (const float*)d_in[10];
    const float* w4 = (const float*)d_in[11];
    const float* b4 = (const float*)d_in[12];
    const float* wz = (const float*)d_in[13];
    const float* bz = (const float*)d_in[14];
    const float* logs = (const float*)d_in[15];
    float* outp = (float*)d_out;
    unsigned int* wsp = (unsigned int*)d_ws;

    prep_kernel<<<58, 64, 0, stream>>>(w0, w1, w2, w3, w4, wz, wsp);
    init_logdet_kernel<<<1, 64, 0, stream>>>(logdet, outp);
    fused_kernel<<<dim3(16, 16, 16), 256, 0, stream>>>(
        input, ft, b0, b1, b2, b3, b4, bz, logs, wsp, outp);
}